// Round 3
// baseline (335.832 us; speedup 1.0000x reference)
//
#include <hip/hip_runtime.h>
#include <math.h>

// BRC loss: per-sample 24x24 Gram of [24][4096] fp32 rows + masked contrastive
// epilogue. Memory-bound in principle (192 MB once, ~30 us floor).
// R3: force 256-VGPR budget (amdgpu_waves_per_eu(2,2)) -- R2's VGPR_Count=128
// vs ~190 live values means acc[]/f[] were spilling to scratch every chunk,
// which is the latency bottleneck both pipes were idling on. LDS already caps
// occupancy at 2 blocks/CU (= 2 waves/SIMD), so 256 VGPRs/wave is free.

#define MROWS 24
#define DIM   4096
#define CH    256            // columns per LDS chunk (1 KB/row = one gll16/row)
#define NCH   (DIM / CH)     // 16 chunks
#define DEPTH 3              // chunk ring buffers in flight
#define PPW   75             // pairs per wave (300 unique pairs / 4 waves)

typedef float f32x4 __attribute__((ext_vector_type(4)));

constexpr int pair_i(int p) {
    int i = 0;
    while (p >= MROWS - i) { p -= MROWS - i; ++i; }
    return i;
}
constexpr int pair_j(int p) {
    int i = 0;
    while (p >= MROWS - i) { p -= MROWS - i; ++i; }
    return i + p;
}

__device__ __forceinline__ void gll16(const float* g, float* l) {
    // async global->LDS, 16B/lane; LDS dest = wave-uniform base + lane*16
    __builtin_amdgcn_global_load_lds(
        (const __attribute__((address_space(1))) unsigned int*)g,
        (__attribute__((address_space(3))) unsigned int*)l, 16, 0, 0);
}

#define WAITV(N) do { \
    asm volatile("s_waitcnt vmcnt(" #N ")" ::: "memory"); \
    __builtin_amdgcn_sched_barrier(0); \
} while (0)

// Compile-time pair indices: keeps f[] and acc[] fully in registers.
template<int W, int P>
__device__ __forceinline__ void accum_pairs(const f32x4* f, float* acc) {
    if constexpr (P < PPW) {
        constexpr int gp = W * PPW + P;
        constexpr int i = pair_i(gp);
        constexpr int j = pair_j(gp);
        #pragma unroll
        for (int s = 0; s < 4; ++s)
            acc[P] = fmaf(f[i][s], f[j][s], acc[P]);
        accum_pairs<W, P + 1>(f, acc);
    }
}

template<int W>
__device__ __forceinline__ void accum_chunk(const float* tile, int lane, float* acc) {
    f32x4 f[MROWS];
    #pragma unroll
    for (int r = 0; r < MROWS; ++r)
        f[r] = *(const f32x4*)(tile + r * CH + lane * 4);
    accum_pairs<W, 0>(f, acc);
}

__global__ __attribute__((amdgpu_flat_work_group_size(256, 256),
                          amdgpu_waves_per_eu(2, 2)))
void brc_loss_kernel(const float* __restrict__ F, float* __restrict__ out, float scale) {
    __shared__ float tile[DEPTH][MROWS * CH];   // 3 x 24 KiB ring
    __shared__ float Gf[MROWS * MROWS];
    __shared__ float inv_n[MROWS];
    __shared__ float rowv[MROWS];

    const int tid  = threadIdx.x;
    const int lane = tid & 63;
    const int wave = tid >> 6;
    const float* base = F + (size_t)blockIdx.x * (MROWS * DIM);

    float acc[PPW];
    #pragma unroll
    for (int p = 0; p < PPW; ++p) acc[p] = 0.0f;

    // stage chunk k into ring slot k%DEPTH (each wave: 6 rows, 1 KB each)
    auto issue = [&](int k) {
        const float* src = base + k * CH + lane * 4;
        float* dst = &tile[k % DEPTH][0];
        #pragma unroll
        for (int q = 0; q < 6; ++q) {
            const int r = wave * 6 + q;
            gll16(src + (size_t)r * DIM, dst + r * CH);
        }
    };

    issue(0); issue(1); issue(2);   // 18 loads in flight per wave

    #pragma unroll 1
    for (int k = 0; k < NCH; ++k) {
        // chunk k's own 6 loads done; newer chunks (k+1,k+2) stay in flight
        if (k < NCH - 2)       WAITV(12);
        else if (k == NCH - 2) WAITV(6);
        else                   WAITV(0);
        __builtin_amdgcn_s_barrier();          // all waves have chunk k staged
        __builtin_amdgcn_sched_barrier(0);

        const float* t = &tile[k % DEPTH][0];
        switch (wave) {
            case 0:  accum_chunk<0>(t, lane, acc); break;
            case 1:  accum_chunk<1>(t, lane, acc); break;
            case 2:  accum_chunk<2>(t, lane, acc); break;
            default: accum_chunk<3>(t, lane, acc); break;
        }
        __builtin_amdgcn_sched_barrier(0);
        __builtin_amdgcn_s_barrier();          // all waves done reading slot k%DEPTH
        if (k + DEPTH < NCH) issue(k + DEPTH); // safe to overwrite that slot
    }

    // cross-lane reduction of 75 per-wave pair accumulators -> Gf
    #pragma unroll
    for (int p = 0; p < PPW; ++p) {
        float v = acc[p];
        #pragma unroll
        for (int off = 32; off; off >>= 1)
            v += __shfl_xor(v, off, 64);
        if (lane == 0) {
            int gp = wave * PPW + p;
            int i = 0, rem = gp;
            while (rem >= MROWS - i) { rem -= MROWS - i; ++i; }
            int j = i + rem;
            Gf[i * MROWS + j] = v;
            Gf[j * MROWS + i] = v;
        }
    }
    __syncthreads();

    if (tid < MROWS)
        inv_n[tid] = 1.0f / fmaxf(sqrtf(Gf[tid * MROWS + tid]), 1e-12f);
    __syncthreads();

    if (tid < MROWS) {
        const int i = tid;
        const int ci = i % 12;
        const float inv_i = inv_n[i];
        float denom = 0.0f, possum = 0.0f;
        int cnt = 0;
        for (int j = 0; j < MROWS; ++j) {
            if (j == i) continue;
            float l = Gf[i * MROWS + j] * inv_i * inv_n[j] * (1.0f / 0.1f);
            denom += expf(l);                       // is_stable=False: no max-sub
            int cj = j % 12;
            int dc = ci - cj; if (dc < 0) dc = -dc;
            if (dc <= 1) { possum += l; ++cnt; }    // tiled tridiagonal positives
        }
        float mean = (possum - (float)cnt * logf(denom)) / ((float)cnt + 1e-6f);
        rowv[i] = -0.1f * mean;                     // -(T/BASE_T) * mean_log_prob_pos
    }
    __syncthreads();

    if (tid == 0) {
        float s = 0.0f;
        #pragma unroll
        for (int i = 0; i < MROWS; ++i) s += rowv[i];
        atomicAdd(out, s * scale);                  // scale = 1/(24*B)
    }
}

extern "C" void kernel_launch(void* const* d_in, const int* in_sizes, int n_in,
                              void* d_out, int out_size, void* d_ws, size_t ws_size,
                              hipStream_t stream) {
    (void)n_in; (void)d_ws; (void)ws_size; (void)out_size;
    // inputs: [0] outputs (unused), [1] targets (unused), [2] features
    const float* F = (const float*)d_in[2];
    float* out = (float*)d_out;
    const int B = in_sizes[2] / (2 * 12 * DIM);   // 512
    const float scale = 1.0f / (24.0f * (float)B);

    hipMemsetAsync(d_out, 0, sizeof(float), stream);   // d_out re-poisoned each call
    brc_loss_kernel<<<dim3(B), dim3(256), 0, stream>>>(F, out, scale);
}

// Round 4
// 300.695 us; speedup vs baseline: 1.1169x; 1.1169x over previous
//
#include <hip/hip_runtime.h>
#include <math.h>

// BRC loss: per-sample 24x24 Gram of [24][4096] fp32 rows + masked contrastive
// epilogue. R4: register-pressure redesign. R1-R3 were latency-bound on AGPR
// parking / remat (128 VGPRs vs ~190 live: f[24]x4 + acc[75]). Now 8 waves,
// wave w owns Gram cols {w, w+8, w+16}: acc<=48 + f_own[3] + f_i ~= 80 live
// regs by construction -> no spills; 4 waves/SIMD for latency hiding.

#define MROWS 24
#define DIM   4096
#define CH    256            // columns per LDS chunk (1 KB/row)
#define NCH   (DIM / CH)     // 16 chunks
#define DEPTH 3              // chunk ring buffers in flight

typedef float f32x4 __attribute__((ext_vector_type(4)));

__device__ __forceinline__ void gll16(const float* g, float* l) {
    // async global->LDS, 16B/lane; LDS dest = wave-uniform base + lane*16
    __builtin_amdgcn_global_load_lds(
        (const __attribute__((address_space(1))) unsigned int*)g,
        (__attribute__((address_space(3))) unsigned int*)l, 16, 0, 0);
}

#define WAITV(N) do { \
    asm volatile("s_waitcnt vmcnt(" #N ")" ::: "memory"); \
    __builtin_amdgcn_sched_barrier(0); \
} while (0)
#define FENCE() __builtin_amdgcn_sched_barrier(0)

// column base in the dump buffer for wave W: sum_{u<W} (3u+27)
__host__ __device__ constexpr int colbase(int W) {
    return 27 * W + 3 * W * (W - 1) / 2;
}

template<int W>
__device__ __forceinline__ void main_loop(const float* base,
                                          float (*tile)[MROWS * CH],
                                          float* red, int lane) {
    constexpr int J0 = W, J1 = W + 8, J2 = W + 16;
    constexpr int N0 = J0 + 1, N1 = J1 + 1, N2 = J2 + 1;
    constexpr int ACCN = N0 + N1 + N2;            // 3W+27, max 48

    float acc[ACCN];
    #pragma unroll
    for (int p = 0; p < ACCN; ++p) acc[p] = 0.0f;

    auto issue = [&](int k) {
        const float* src = base + k * CH + lane * 4;
        float* dst = &tile[k % DEPTH][0];
        #pragma unroll
        for (int q = 0; q < 3; ++q) {
            const int r = 3 * W + q;               // each wave stages 3 rows
            gll16(src + (size_t)r * DIM, dst + r * CH);
        }
    };

    issue(0); issue(1); issue(2);                  // 9 loads in flight

    #pragma unroll 1
    for (int k = 0; k < NCH; ++k) {
        if (k <= NCH - 3)      WAITV(6);           // chunk k's 3 loads done
        else if (k == NCH - 2) WAITV(3);
        else                   WAITV(0);
        __builtin_amdgcn_s_barrier();              // chunk k staged by all waves
        FENCE();

        const float* t = &tile[k % DEPTH][0] + lane * 4;
        f32x4 f0 = *(const f32x4*)(t + J0 * CH);
        f32x4 f1 = *(const f32x4*)(t + J1 * CH);
        f32x4 f2 = *(const f32x4*)(t + J2 * CH);
        #pragma unroll
        for (int i = 0; i < MROWS; ++i) {
            f32x4 fi = *(const f32x4*)(t + i * CH);
            if (i <= J0) {
                #pragma unroll
                for (int e = 0; e < 4; ++e) acc[i] = fmaf(fi[e], f0[e], acc[i]);
            }
            if (i <= J1) {
                #pragma unroll
                for (int e = 0; e < 4; ++e) acc[N0 + i] = fmaf(fi[e], f1[e], acc[N0 + i]);
            }
            if (i <= J2) {
                #pragma unroll
                for (int e = 0; e < 4; ++e) acc[N0 + N1 + i] = fmaf(fi[e], f2[e], acc[N0 + N1 + i]);
            }
        }
        FENCE();
        __builtin_amdgcn_s_barrier();              // all waves done with slot
        if (k + DEPTH < NCH) issue(k + DEPTH);     // overwrite freed slot
    }

    // fold 64 -> 32 lane-partials, dump to red[col*32 + lane] (tile is dead)
    #pragma unroll
    for (int p = 0; p < ACCN; ++p)
        acc[p] += __shfl_xor(acc[p], 32, 64);
    if (lane < 32) {
        #pragma unroll
        for (int p = 0; p < ACCN; ++p)
            red[(colbase(W) + p) * 32 + lane] = acc[p];
    }
}

__global__ __launch_bounds__(512, 4)
void brc_loss_kernel(const float* __restrict__ F, float* __restrict__ out, float scale) {
    __shared__ float tile[DEPTH][MROWS * CH];   // 72 KiB ring; reused as dump buf
    __shared__ float Gf[MROWS * MROWS];
    __shared__ float inv_n[MROWS];
    __shared__ float rowv[MROWS];

    const int tid  = threadIdx.x;
    const int lane = tid & 63;
    const int wave = tid >> 6;
    const float* base = F + (size_t)blockIdx.x * (MROWS * DIM);
    float* red = &tile[0][0];                   // 300*32 floats = 37.5 KiB, fits

    switch (wave) {
        case 0:  main_loop<0>(base, tile, red, lane); break;
        case 1:  main_loop<1>(base, tile, red, lane); break;
        case 2:  main_loop<2>(base, tile, red, lane); break;
        case 3:  main_loop<3>(base, tile, red, lane); break;
        case 4:  main_loop<4>(base, tile, red, lane); break;
        case 5:  main_loop<5>(base, tile, red, lane); break;
        case 6:  main_loop<6>(base, tile, red, lane); break;
        default: main_loop<7>(base, tile, red, lane); break;
    }
    __syncthreads();                            // dump complete

    // reduce 300 columns of 32 partials -> Gf (staggered reads: conflict-free)
    if (tid < 300) {
        float s = 0.0f;
        #pragma unroll
        for (int l = 0; l < 32; ++l)
            s += red[tid * 32 + ((l + tid) & 31)];
        // decode column -> (i, j)
        int W = 0;
        while (W < 7 && tid >= colbase(W + 1)) ++W;
        int p = tid - colbase(W);
        int i, j;
        if (p <= W)               { j = W;      i = p; }
        else if (p <= 2 * W + 9)  { j = W + 8;  i = p - (W + 1); }
        else                      { j = W + 16; i = p - (2 * W + 10); }
        Gf[i * MROWS + j] = s;
        Gf[j * MROWS + i] = s;
    }
    __syncthreads();

    if (tid < MROWS)
        inv_n[tid] = 1.0f / fmaxf(sqrtf(Gf[tid * MROWS + tid]), 1e-12f);
    __syncthreads();

    if (tid < MROWS) {
        const int i = tid;
        const int ci = i % 12;
        const float inv_i = inv_n[i];
        float denom = 0.0f, possum = 0.0f;
        int cnt = 0;
        for (int j = 0; j < MROWS; ++j) {
            if (j == i) continue;
            float l = Gf[i * MROWS + j] * inv_i * inv_n[j] * (1.0f / 0.1f);
            denom += expf(l);                       // is_stable=False: no max-sub
            int cj = j % 12;
            int dc = ci - cj; if (dc < 0) dc = -dc;
            if (dc <= 1) { possum += l; ++cnt; }    // tiled tridiagonal positives
        }
        float mean = (possum - (float)cnt * logf(denom)) / ((float)cnt + 1e-6f);
        rowv[i] = -0.1f * mean;                     // -(T/BASE_T) * mean_log_prob_pos
    }
    __syncthreads();

    if (tid == 0) {
        float s = 0.0f;
        #pragma unroll
        for (int i = 0; i < MROWS; ++i) s += rowv[i];
        atomicAdd(out, s * scale);                  // scale = 1/(24*B)
    }
}

extern "C" void kernel_launch(void* const* d_in, const int* in_sizes, int n_in,
                              void* d_out, int out_size, void* d_ws, size_t ws_size,
                              hipStream_t stream) {
    (void)n_in; (void)d_ws; (void)ws_size; (void)out_size;
    // inputs: [0] outputs (unused), [1] targets (unused), [2] features
    const float* F = (const float*)d_in[2];
    float* out = (float*)d_out;
    const int B = in_sizes[2] / (2 * 12 * DIM);   // 512
    const float scale = 1.0f / (24.0f * (float)B);

    hipMemsetAsync(d_out, 0, sizeof(float), stream);   // d_out re-poisoned each call
    brc_loss_kernel<<<dim3(B), dim3(512), 0, stream>>>(F, out, scale);
}